// Round 1
// baseline (52679.089 us; speedup 1.0000x reference)
//
#include <hip/hip_runtime.h>
#include <math.h>

#define T_SEQ 2048
#define S_SEQ 2050   // T + 2
#define NTAG 12
#define START_TAG 10
#define STOP_TAG 11
#define NBLK 32      // blocks per LSTM stream

// ---------------------------------------------------------------------------
// Generic fp32 GEMM: C[M,N] = Aacc[M,K] @ W[N,K]^T + bias, fused epilogues.
// amode 0: A[r][k] direct (row r possibly reversed). amode 1: concat of two
// h-buffers: lo[r] = concat(Hf[r], Hb[S-1-r]).
// epi 0: +bias; 1: elu(+bias)+Aacc(m,n) residual; 2: elu(+bias); 3: (+bias)*MUL
// ---------------------------------------------------------------------------
struct GemmP {
  const float* W; const float* bias; float* C;
  int M, N, K;
  int amode; const float* A; int lda; int rev; int rowoff;
  const float* Hf; const float* Hb;
  int epi; const float* MUL;
};

__device__ __forceinline__ float aacc(const GemmP& p, int m, int k) {
  int r = p.rowoff + m;
  if (p.rev) r = (S_SEQ - 1) - r;
  if (p.amode == 0) return p.A[(size_t)r * p.lda + k];
  return (k < 512) ? p.Hf[(size_t)r * 512 + k]
                   : p.Hb[(size_t)(S_SEQ - 1 - r) * 512 + (k - 512)];
}

__global__ __launch_bounds__(256) void gemm_k(GemmP p) {
  __shared__ float As[16][136];
  __shared__ float Bs[16][136];
  const int t  = threadIdx.x;
  const int tx = t & 15, ty = t >> 4;
  const int m0 = blockIdx.y * 128, n0 = blockIdx.x * 128;

  float acc[8][8];
#pragma unroll
  for (int i = 0; i < 8; ++i)
#pragma unroll
    for (int j = 0; j < 8; ++j) acc[i][j] = 0.f;

  const int KT  = (p.K + 15) >> 4;
  const int kk  = t & 15;
  const int sub = t >> 4;

  for (int kt = 0; kt < KT; ++kt) {
    const int k   = (kt << 4) + kk;
    const bool kok = (k < p.K);
#pragma unroll
    for (int l = 0; l < 8; ++l) {
      int mm = sub * 8 + l;
      int m = m0 + mm;
      As[kk][mm] = (kok && m < p.M) ? aacc(p, m, k) : 0.f;
      int n = n0 + mm;
      Bs[kk][mm] = (kok && n < p.N) ? p.W[(size_t)n * p.K + k] : 0.f;
    }
    __syncthreads();
#pragma unroll
    for (int q = 0; q < 16; ++q) {
      const float4 a0 = *(const float4*)&As[q][ty * 4];
      const float4 a1 = *(const float4*)&As[q][64 + ty * 4];
      const float4 b0 = *(const float4*)&Bs[q][tx * 4];
      const float4 b1 = *(const float4*)&Bs[q][64 + tx * 4];
      const float av[8] = {a0.x, a0.y, a0.z, a0.w, a1.x, a1.y, a1.z, a1.w};
      const float bv[8] = {b0.x, b0.y, b0.z, b0.w, b1.x, b1.y, b1.z, b1.w};
#pragma unroll
      for (int i = 0; i < 8; ++i)
#pragma unroll
        for (int j = 0; j < 8; ++j) acc[i][j] += av[i] * bv[j];
    }
    __syncthreads();
  }

#pragma unroll
  for (int i = 0; i < 8; ++i) {
    int m = m0 + (i < 4 ? ty * 4 + i : 64 + ty * 4 + (i - 4));
    if (m >= p.M) continue;
#pragma unroll
    for (int j = 0; j < 8; ++j) {
      int n = n0 + (j < 4 ? tx * 4 + j : 64 + tx * 4 + (j - 4));
      if (n >= p.N) continue;
      float v = acc[i][j] + p.bias[n];
      if (p.epi == 1)      v = (v > 0.f ? v : expm1f(v)) + aacc(p, m, n);
      else if (p.epi == 2) v = (v > 0.f ? v : expm1f(v));
      else if (p.epi == 3) v = v * p.MUL[(size_t)m * p.N + n];
      p.C[(size_t)m * p.N + n] = v;
    }
  }
}

// ---------------------------------------------------------------------------
// Persistent recurrent LSTM layer: 4 streams (lstm x dir), NBLK blocks each.
// Block b of stream s owns h indices [16b,16b+16) -> 64 gate rows.
// Weights register-resident: thread (og=t>>5, p=t&31) holds w[8 outs][16 elems]
// with h-slice {p + 32e}. Per-step grid sync via agent-scope atomics.
// ---------------------------------------------------------------------------
__global__ __launch_bounds__(256) void lstm_layer_k(
    const float* __restrict__ Whh_u, const float* __restrict__ Whh_p,
    const float* __restrict__ XP,    // [4][S_SEQ][2048]
    float* __restrict__ Hout,        // [4][S_SEQ][512]
    int* __restrict__ cnt,           // [4][S_SEQ]
    int layer) {
  const int bid = blockIdx.x;
  const int s = bid & 3;        // stream: (lstm<<1)|dir
  const int b = bid >> 2;       // 0..NBLK-1
  const int t = threadIdx.x;    // 0..255
  const int p = t & 31;
  const int og = t >> 5;        // 0..7

  const float* W2 = ((s >> 1) ? Whh_p : Whh_u) +
                    (size_t)(layer * 2 + (s & 1)) * 2048 * 512;
  const float* xp = XP + (size_t)s * S_SEQ * 2048;
  float* hout = Hout + (size_t)s * S_SEQ * 512;
  int* c_ = cnt + s * S_SEQ;

  __shared__ float h_lds[512];
  __shared__ float xp_lds[64];
  __shared__ float gates[64];

  // Register-resident weights (fully statically indexed).
  float w[8][16];
#pragma unroll
  for (int oo = 0; oo < 8; ++oo) {
    const int o = og * 8 + oo;
    const int row = ((o >> 4) << 9) + (b << 4) + (o & 15);
    const float* wr = W2 + (size_t)row * 512 + p;
#pragma unroll
    for (int e = 0; e < 16; ++e) w[oo][e] = wr[e << 5];
  }

  for (int i = t; i < 512; i += 256) h_lds[i] = 0.f;
  float creg = 0.f;
  __syncthreads();

  for (int step = 0; step < S_SEQ; ++step) {
    if (t < 64) {
      const int row = ((t >> 4) << 9) + (b << 4) + (t & 15);
      xp_lds[t] = xp[(size_t)step * 2048 + row];
    }
    __syncthreads();

    float acc[8];
#pragma unroll
    for (int oo = 0; oo < 8; ++oo) acc[oo] = 0.f;
#pragma unroll
    for (int e = 0; e < 16; ++e) {
      const float hv = h_lds[p + (e << 5)];
#pragma unroll
      for (int oo = 0; oo < 8; ++oo) acc[oo] += w[oo][e] * hv;
    }
#pragma unroll
    for (int d = 16; d >= 1; d >>= 1) {
#pragma unroll
      for (int oo = 0; oo < 8; ++oo) acc[oo] += __shfl_xor(acc[oo], d, 64);
    }
    if (p == 0) {
#pragma unroll
      for (int oo = 0; oo < 8; ++oo) {
        const int o = og * 8 + oo;
        gates[o] = acc[oo] + xp_lds[o];
      }
    }
    __syncthreads();

    if (t < 16) {
      const float gi = gates[t], gf = gates[16 + t];
      const float gg = gates[32 + t], go = gates[48 + t];
      const float si = 1.f / (1.f + __expf(-gi));
      const float sf = 1.f / (1.f + __expf(-gf));
      const float so = 1.f / (1.f + __expf(-go));
      creg = sf * creg + si * tanhf(gg);
      const float h = so * tanhf(creg);
      __hip_atomic_store(&hout[(size_t)step * 512 + (b << 4) + t], h,
                         __ATOMIC_RELAXED, __HIP_MEMORY_SCOPE_AGENT);
    }
    __threadfence();
    __syncthreads();
    if (t == 0) {
      __hip_atomic_fetch_add(&c_[step], 1, __ATOMIC_RELEASE,
                             __HIP_MEMORY_SCOPE_AGENT);
      while (__hip_atomic_load(&c_[step], __ATOMIC_ACQUIRE,
                               __HIP_MEMORY_SCOPE_AGENT) < NBLK)
        __builtin_amdgcn_s_sleep(1);
    }
    __syncthreads();
    {
      const float v0 = __hip_atomic_load(&hout[(size_t)step * 512 + t],
                                         __ATOMIC_RELAXED,
                                         __HIP_MEMORY_SCOPE_AGENT);
      const float v1 = __hip_atomic_load(&hout[(size_t)step * 512 + 256 + t],
                                         __ATOMIC_RELAXED,
                                         __HIP_MEMORY_SCOPE_AGENT);
      h_lds[t] = v0;
      h_lds[256 + t] = v1;
    }
  }
}

// ---------------------------------------------------------------------------
// CRF: sequential scans (wave0 unary, wave1 pairwise) + score gathers
// (waves 2/3), then combine. Single block; in-wave lockstep avoids barriers.
// ---------------------------------------------------------------------------
__global__ __launch_bounds__(256) void crf_k(const float* __restrict__ FU,
                                             const float* __restrict__ FPp,
                                             const float* __restrict__ trans,
                                             const int* __restrict__ tags,
                                             float* __restrict__ out) {
  __shared__ float tr[144];
  __shared__ float fvU[NTAG];
  __shared__ float fvP[NTAG];
  __shared__ float pf[160];
  __shared__ float sc[2];
  const int t = threadIdx.x;
  if (t < 144) tr[t] = trans[t];
  if (t < NTAG) {
    fvU[t] = (t == START_TAG) ? 0.f : -100.f;
    fvP[t] = 0.f;
  }
  __syncthreads();
  const int w = t >> 6, l = t & 63;

  if (w == 0) {  // unary forward scan
    float featc = (l < NTAG) ? FU[l] : 0.f;
    for (int step = 0; step < T_SEQ; ++step) {
      float featn = 0.f;
      if (l < NTAG && step + 1 < T_SEQ) featn = FU[(size_t)(step + 1) * NTAG + l];
      if (l < NTAG) {
        float m = -1e30f;
#pragma unroll
        for (int i = 0; i < NTAG; ++i) m = fmaxf(m, fvU[i] + tr[i * NTAG + l]);
        float ss = 0.f;
#pragma unroll
        for (int i = 0; i < NTAG; ++i)
          ss += __expf(fvU[i] + tr[i * NTAG + l] - m);
        fvU[l] = m + __logf(ss) + featc;
      }
      featc = featn;
    }
  } else if (w == 1) {  // pairwise forward scan
    for (int q = l; q < 144; q += 64) pf[q] = FPp[q];
    for (int step = 0; step < T_SEQ + 1; ++step) {
      float nx0 = 0.f, nx1 = 0.f, nx2 = 0.f;
      if (step + 1 < T_SEQ + 1) {
        const float* src = FPp + (size_t)(step + 1) * 144;
        nx0 = src[l];
        nx1 = src[l + 64];
        if (l < 16) nx2 = src[l + 128];
      }
      float nf = 0.f;
      if (l < NTAG) {
        float m = -1e30f;
#pragma unroll
        for (int i = 0; i < NTAG; ++i) m = fmaxf(m, fvP[i] + pf[i * NTAG + l]);
        float ss = 0.f;
#pragma unroll
        for (int i = 0; i < NTAG; ++i)
          ss += __expf(fvP[i] + pf[i * NTAG + l] - m);
        nf = m + __logf(ss);
      }
      pf[l] = nx0;
      pf[l + 64] = nx1;
      if (l < 16) pf[l + 128] = nx2;
      if (l < NTAG) fvP[l] = nf;
    }
  } else if (w == 2) {  // score_u
    float acc = 0.f;
    for (int i = l; i < T_SEQ; i += 64) {
      const int tg = tags[i];
      const int pv = (i == 0) ? START_TAG : tags[i - 1];
      acc += FU[(size_t)i * NTAG + tg] + tr[pv * NTAG + tg];
    }
    if (l == 0) acc += tr[tags[T_SEQ - 1] * NTAG + STOP_TAG];
#pragma unroll
    for (int d = 32; d >= 1; d >>= 1) acc += __shfl_xor(acc, d, 64);
    if (l == 0) sc[0] = acc;
  } else {  // score_p
    float acc = 0.f;
    for (int i = l; i < T_SEQ + 1; i += 64) {
      const int a = (i == 0) ? START_TAG : tags[i - 1];
      const int b2 = (i < T_SEQ) ? tags[i] : STOP_TAG;
      acc += FPp[(size_t)i * 144 + a * NTAG + b2];
    }
#pragma unroll
    for (int d = 32; d >= 1; d >>= 1) acc += __shfl_xor(acc, d, 64);
    if (l == 0) sc[1] = acc;
  }
  __syncthreads();
  if (t == 0) {
    float m = -1e30f;
    for (int i = 0; i < NTAG; ++i)
      m = fmaxf(m, fvU[i] + tr[i * NTAG + STOP_TAG]);
    float ss = 0.f;
    for (int i = 0; i < NTAG; ++i)
      ss += __expf(fvU[i] + tr[i * NTAG + STOP_TAG] - m);
    const float alpha_u = m + __logf(ss);
    float m2 = -1e30f;
    for (int i = 0; i < NTAG; ++i) m2 = fmaxf(m2, fvP[i]);
    float s2 = 0.f;
    for (int i = 0; i < NTAG; ++i) s2 += __expf(fvP[i] - m2);
    const float alpha_p = m2 + __logf(s2);
    out[0] = alpha_u - sc[0] + alpha_p - sc[1];
  }
}

// ---------------------------------------------------------------------------
// Workspace layout (float offsets)
// ---------------------------------------------------------------------------
static const size_t F_XP  = 0;                         // 4*2050*2048
static const size_t F_H0  = 16793600;                  // 4*2050*512
static const size_t F_H1  = 20992000;                  // 4*2050*512
static const size_t F_FC  = 25190400;                  // 2048*1024
static const size_t F_FU  = 27287552;                  // 2048*12
static const size_t F_UB  = 27312128;                  // 2049*512
static const size_t F_HP  = 28361216;                  // 2049*512
static const size_t F_FI  = 29410304;                  // 2049*300
static const size_t F_FO  = 30025004;                  // 2049*300
static const size_t F_FP  = 30639704;                  // 2049*144
static const size_t F_CNT = 30934760;                  // 2*4*2050 ints

extern "C" void kernel_launch(void* const* d_in, const int* in_sizes, int n_in,
                              void* d_out, int out_size, void* d_ws,
                              size_t ws_size, hipStream_t stream) {
  (void)in_sizes; (void)n_in; (void)out_size; (void)ws_size;
  const float* embeds = (const float*)d_in[0];
  const int*   tags   = (const int*)d_in[1];
  const float* uWih   = (const float*)d_in[2];
  const float* uWhh   = (const float*)d_in[3];
  const float* ub     = (const float*)d_in[4];
  const float* pWih   = (const float*)d_in[5];
  const float* pWhh   = (const float*)d_in[6];
  const float* pb     = (const float*)d_in[7];
  const float* ufcW   = (const float*)d_in[8];
  const float* ufcb   = (const float*)d_in[9];
  const float* h2tW   = (const float*)d_in[10];
  const float* h2tb   = (const float*)d_in[11];
  const float* trans  = (const float*)d_in[12];
  const float* UW     = (const float*)d_in[13];
  const float* Ub     = (const float*)d_in[14];
  const float* VW     = (const float*)d_in[15];
  const float* Vb     = (const float*)d_in[16];
  const float* PW     = (const float*)d_in[17];
  const float* Pb     = (const float*)d_in[18];
  const float* pwW    = (const float*)d_in[19];
  const float* pwb    = (const float*)d_in[20];
  const float* ppW    = (const float*)d_in[21];
  const float* ppb    = (const float*)d_in[22];
  float* out = (float*)d_out;
  float* F = (float*)d_ws;
  int* CNT = (int*)(F + F_CNT);

  (void)hipMemsetAsync(CNT, 0, (size_t)2 * 4 * S_SEQ * sizeof(int), stream);

  auto launch = [&](const GemmP& p) {
    dim3 g((p.N + 127) / 128, (p.M + 127) / 128);
    gemm_k<<<g, 256, 0, stream>>>(p);
  };

  // ---- layer-0 xp (4 streams) ----
  for (int s = 0; s < 4; ++s) {
    const int lstm = s >> 1, d = s & 1;
    GemmP p{};
    p.W    = (lstm ? pWih : uWih) + (size_t)d * 2048 * 1024;
    p.bias = (lstm ? pb : ub) + (size_t)d * 2048;
    p.C = F + F_XP + (size_t)s * S_SEQ * 2048;
    p.M = S_SEQ; p.N = 2048; p.K = 1024;
    p.amode = 0; p.A = embeds; p.lda = 1024; p.rev = d; p.rowoff = 0;
    p.epi = 0;
    launch(p);
  }
  lstm_layer_k<<<4 * NBLK, 256, 0, stream>>>(uWhh, pWhh, F + F_XP, F + F_H0,
                                             CNT, 0);
  // ---- layer-1 xp ----
  for (int s = 0; s < 4; ++s) {
    const int lstm = s >> 1, d = s & 1;
    GemmP p{};
    p.W    = (lstm ? pWih : uWih) + (size_t)(2 + d) * 2048 * 1024;
    p.bias = (lstm ? pb : ub) + (size_t)(2 + d) * 2048;
    p.C = F + F_XP + (size_t)s * S_SEQ * 2048;
    p.M = S_SEQ; p.N = 2048; p.K = 1024;
    p.amode = 1; p.rev = d; p.rowoff = 0;
    p.Hf = F + F_H0 + (size_t)(lstm * 2 + 0) * S_SEQ * 512;
    p.Hb = F + F_H0 + (size_t)(lstm * 2 + 1) * S_SEQ * 512;
    p.epi = 0;
    launch(p);
  }
  lstm_layer_k<<<4 * NBLK, 256, 0, stream>>>(uWhh, pWhh, F + F_XP, F + F_H1,
                                             CNT + 4 * S_SEQ, 1);
  // ---- unary head ----
  {
    GemmP p{};
    p.W = ufcW; p.bias = ufcb; p.C = F + F_FC;
    p.M = 2048; p.N = 1024; p.K = 1024;
    p.amode = 1; p.rev = 0; p.rowoff = 1;
    p.Hf = F + F_H1; p.Hb = F + F_H1 + (size_t)1 * S_SEQ * 512;
    p.epi = 1;
    launch(p);
  }
  {
    GemmP p{};
    p.W = h2tW; p.bias = h2tb; p.C = F + F_FU;
    p.M = 2048; p.N = 12; p.K = 1024;
    p.amode = 0; p.A = F + F_FC; p.lda = 1024; p.rev = 0; p.rowoff = 0;
    p.epi = 0;
    launch(p);
  }
  // ---- pairwise head ----
  {
    GemmP p{};
    p.W = UW; p.bias = Ub; p.C = F + F_UB;
    p.M = 2049; p.N = 512; p.K = 1024;
    p.amode = 1; p.rev = 0; p.rowoff = 0;
    p.Hf = F + F_H1 + (size_t)2 * S_SEQ * 512;
    p.Hb = F + F_H1 + (size_t)3 * S_SEQ * 512;
    p.epi = 0;
    launch(p);
  }
  {
    GemmP p{};
    p.W = VW; p.bias = Vb; p.C = F + F_HP;
    p.M = 2049; p.N = 512; p.K = 1024;
    p.amode = 1; p.rev = 0; p.rowoff = 1;
    p.Hf = F + F_H1 + (size_t)2 * S_SEQ * 512;
    p.Hb = F + F_H1 + (size_t)3 * S_SEQ * 512;
    p.epi = 3; p.MUL = F + F_UB;
    launch(p);
  }
  {
    GemmP p{};
    p.W = PW; p.bias = Pb; p.C = F + F_FI;
    p.M = 2049; p.N = 300; p.K = 512;
    p.amode = 0; p.A = F + F_HP; p.lda = 512; p.rev = 0; p.rowoff = 0;
    p.epi = 2;
    launch(p);
  }
  {
    GemmP p{};
    p.W = pwW; p.bias = pwb; p.C = F + F_FO;
    p.M = 2049; p.N = 300; p.K = 300;
    p.amode = 0; p.A = F + F_FI; p.lda = 300; p.rev = 0; p.rowoff = 0;
    p.epi = 1;
    launch(p);
  }
  {
    GemmP p{};
    p.W = ppW; p.bias = ppb; p.C = F + F_FP;
    p.M = 2049; p.N = 144; p.K = 300;
    p.amode = 0; p.A = F + F_FO; p.lda = 300; p.rev = 0; p.rowoff = 0;
    p.epi = 0;
    launch(p);
  }
  crf_k<<<1, 256, 0, stream>>>(F + F_FU, F + F_FP, trans, tags, out);
}

// Round 3
// 15172.543 us; speedup vs baseline: 3.4720x; 3.4720x over previous
//
#include <hip/hip_runtime.h>
#include <math.h>

#define T_SEQ 2048
#define S_SEQ 2050   // T + 2
#define NTAG 12
#define START_TAG 10
#define STOP_TAG 11
#define NBLK 32      // blocks per LSTM stream

// ---------------------------------------------------------------------------
// Generic fp32 GEMM: C[M,N] = Aacc[M,K] @ W[N,K]^T + bias, fused epilogues.
// amode 0: A[r][k] direct (row r possibly reversed). amode 1: concat of two
// h-buffers: lo[r] = concat(Hf[r], Hb[S-1-r]).
// epi 0: +bias; 1: elu(+bias)+Aacc(m,n) residual; 2: elu(+bias); 3: (+bias)*MUL
// When launched with gridDim.z > 1, per-z pointer arrays override W/bias/C/
// Hf/Hb/rev (batches the 4 independent (lstm,dir) streams in one dispatch).
// ---------------------------------------------------------------------------
struct GemmP {
  const float* W; const float* bias; float* C;
  int M, N, K;
  int amode; const float* A; int lda; int rev; int rowoff;
  const float* Hf; const float* Hb;
  int epi; const float* MUL;
  const float* Wz[4]; const float* biasz[4]; float* Cz[4];
  const float* Hfz[4]; const float* Hbz[4]; int revz[4];
};

__device__ __forceinline__ float aacc(const GemmP& p, int m, int k) {
  int r = p.rowoff + m;
  if (p.rev) r = (S_SEQ - 1) - r;
  if (p.amode == 0) return p.A[(size_t)r * p.lda + k];
  return (k < 512) ? p.Hf[(size_t)r * 512 + k]
                   : p.Hb[(size_t)(S_SEQ - 1 - r) * 512 + (k - 512)];
}

__global__ __launch_bounds__(256) void gemm_k(GemmP p) {
  if (gridDim.z > 1) {
    const int z = blockIdx.z;
    p.W = p.Wz[z]; p.bias = p.biasz[z]; p.C = p.Cz[z];
    p.Hf = p.Hfz[z]; p.Hb = p.Hbz[z]; p.rev = p.revz[z];
  }
  __shared__ float As[16][136];
  __shared__ float Bs[16][136];
  const int t  = threadIdx.x;
  const int tx = t & 15, ty = t >> 4;
  const int m0 = blockIdx.y * 128, n0 = blockIdx.x * 128;

  float acc[8][8];
#pragma unroll
  for (int i = 0; i < 8; ++i)
#pragma unroll
    for (int j = 0; j < 8; ++j) acc[i][j] = 0.f;

  const int KT  = (p.K + 15) >> 4;
  const int kk  = t & 15;
  const int sub = t >> 4;

  for (int kt = 0; kt < KT; ++kt) {
    const int k   = (kt << 4) + kk;
    const bool kok = (k < p.K);
#pragma unroll
    for (int l = 0; l < 8; ++l) {
      int mm = sub * 8 + l;
      int m = m0 + mm;
      As[kk][mm] = (kok && m < p.M) ? aacc(p, m, k) : 0.f;
      int n = n0 + mm;
      Bs[kk][mm] = (kok && n < p.N) ? p.W[(size_t)n * p.K + k] : 0.f;
    }
    __syncthreads();
#pragma unroll
    for (int q = 0; q < 16; ++q) {
      const float4 a0 = *(const float4*)&As[q][ty * 4];
      const float4 a1 = *(const float4*)&As[q][64 + ty * 4];
      const float4 b0 = *(const float4*)&Bs[q][tx * 4];
      const float4 b1 = *(const float4*)&Bs[q][64 + tx * 4];
      const float av[8] = {a0.x, a0.y, a0.z, a0.w, a1.x, a1.y, a1.z, a1.w};
      const float bv[8] = {b0.x, b0.y, b0.z, b0.w, b1.x, b1.y, b1.z, b1.w};
#pragma unroll
      for (int i = 0; i < 8; ++i)
#pragma unroll
        for (int j = 0; j < 8; ++j) acc[i][j] += av[i] * bv[j];
    }
    __syncthreads();
  }

#pragma unroll
  for (int i = 0; i < 8; ++i) {
    int m = m0 + (i < 4 ? ty * 4 + i : 64 + ty * 4 + (i - 4));
    if (m >= p.M) continue;
#pragma unroll
    for (int j = 0; j < 8; ++j) {
      int n = n0 + (j < 4 ? tx * 4 + j : 64 + tx * 4 + (j - 4));
      if (n >= p.N) continue;
      float v = acc[i][j] + p.bias[n];
      if (p.epi == 1)      v = (v > 0.f ? v : expm1f(v)) + aacc(p, m, n);
      else if (p.epi == 2) v = (v > 0.f ? v : expm1f(v));
      else if (p.epi == 3) v = v * p.MUL[(size_t)m * p.N + n];
      p.C[(size_t)m * p.N + n] = v;
    }
  }
}

// ---------------------------------------------------------------------------
// Persistent recurrent LSTM layer: 4 streams (lstm x dir), NBLK blocks each.
// Block b of stream s owns h indices [16b,16b+16) -> 64 gate rows.
// Weights register-resident (launch_bounds(.,1) opens the VGPR budget).
// Cross-block traffic exclusively via relaxed agent-scope atomics (sc0/sc1
// write-through to IF$, coherent, NO wbl2/inv fences); ordering of
// h-stores before the counter add is program order within wave 0 after an
// explicit s_waitcnt vmcnt(0).
// ---------------------------------------------------------------------------
__global__ __launch_bounds__(256, 1) void lstm_layer_k(
    const float* __restrict__ Whh_u, const float* __restrict__ Whh_p,
    const float* __restrict__ XP,    // [4][S_SEQ][2048]
    float* __restrict__ Hout,        // [4][S_SEQ][512]
    int* __restrict__ cnt,           // [4][S_SEQ]
    int layer) {
  const int bid = blockIdx.x;
  const int s = bid & 3;        // stream: (lstm<<1)|dir
  const int b = bid >> 2;       // 0..NBLK-1
  const int t = threadIdx.x;    // 0..255
  const int p = t & 31;
  const int og = t >> 5;        // 0..7

  const float* W2 = ((s >> 1) ? Whh_p : Whh_u) +
                    (size_t)(layer * 2 + (s & 1)) * 2048 * 512;
  const float* xp = XP + (size_t)s * S_SEQ * 2048;
  float* hout = Hout + (size_t)s * S_SEQ * 512;
  int* c_ = cnt + s * S_SEQ;

  __shared__ float h_lds[512];
  __shared__ float xp_lds[64];
  __shared__ float gates[64];

  // Register-resident weights (fully statically indexed).
  float w[8][16];
#pragma unroll
  for (int oo = 0; oo < 8; ++oo) {
    const int o = og * 8 + oo;
    const int row = ((o >> 4) << 9) + (b << 4) + (o & 15);
    const float* wr = W2 + (size_t)row * 512 + p;
#pragma unroll
    for (int e = 0; e < 16; ++e) w[oo][e] = wr[e << 5];
  }

  const int row64 = ((t >> 4) << 9) + (b << 4) + (t & 15);  // for t<64
  float xr = (t < 64) ? xp[row64] : 0.f;

  for (int i = t; i < 512; i += 256) h_lds[i] = 0.f;
  float creg = 0.f;
  __syncthreads();

  for (int step = 0; step < S_SEQ; ++step) {
    if (t < 64) xp_lds[t] = xr;   // xp for current step
    __syncthreads();              // xp_lds + h_lds ready

    // prefetch next step's xp into register (hidden under the dot product)
    if (t < 64 && step + 1 < S_SEQ)
      xr = xp[(size_t)(step + 1) * 2048 + row64];

    float acc[8];
#pragma unroll
    for (int oo = 0; oo < 8; ++oo) acc[oo] = 0.f;
#pragma unroll
    for (int e = 0; e < 16; ++e) {
      const float hv = h_lds[p + (e << 5)];
#pragma unroll
      for (int oo = 0; oo < 8; ++oo) acc[oo] += w[oo][e] * hv;
    }
#pragma unroll
    for (int d = 16; d >= 1; d >>= 1) {
#pragma unroll
      for (int oo = 0; oo < 8; ++oo) acc[oo] += __shfl_xor(acc[oo], d, 64);
    }
    if (p == 0) {
#pragma unroll
      for (int oo = 0; oo < 8; ++oo) {
        const int o = og * 8 + oo;
        gates[o] = acc[oo] + xp_lds[o];
      }
    }
    __syncthreads();

    if (t < 16) {
      const float gi = gates[t], gf = gates[16 + t];
      const float gg = gates[32 + t], go = gates[48 + t];
      const float si = 1.f / (1.f + __expf(-gi));
      const float sf = 1.f / (1.f + __expf(-gf));
      const float so = 1.f / (1.f + __expf(-go));
      creg = sf * creg + si * tanhf(gg);
      const float h = so * tanhf(creg);
      __hip_atomic_store(&hout[(size_t)step * 512 + (b << 4) + t], h,
                         __ATOMIC_RELAXED, __HIP_MEMORY_SCOPE_AGENT);
    }
    // Drain write-through stores (and the xp prefetch) to the coherence
    // point. Storing lanes (t<16) and the signaling lane (t==0) are in the
    // same wave -> program order suffices after this wait.
    asm volatile("s_waitcnt vmcnt(0)" ::: "memory");
    if (t == 0) {
      __hip_atomic_fetch_add(&c_[step], 1, __ATOMIC_RELAXED,
                             __HIP_MEMORY_SCOPE_AGENT);
      while (__hip_atomic_load(&c_[step], __ATOMIC_RELAXED,
                               __HIP_MEMORY_SCOPE_AGENT) < NBLK) {
      }
    }
    __syncthreads();
    {
      const float v0 = __hip_atomic_load(&hout[(size_t)step * 512 + t],
                                         __ATOMIC_RELAXED,
                                         __HIP_MEMORY_SCOPE_AGENT);
      const float v1 = __hip_atomic_load(&hout[(size_t)step * 512 + 256 + t],
                                         __ATOMIC_RELAXED,
                                         __HIP_MEMORY_SCOPE_AGENT);
      h_lds[t] = v0;
      h_lds[256 + t] = v1;
    }
    // loop-top __syncthreads() orders these h_lds writes before next reads
  }
}

// ---------------------------------------------------------------------------
// CRF: sequential scans (wave0 unary, wave1 pairwise) + score gathers
// (waves 2/3), then combine. Single block; in-wave lockstep avoids barriers.
// ---------------------------------------------------------------------------
__global__ __launch_bounds__(256) void crf_k(const float* __restrict__ FU,
                                             const float* __restrict__ FPp,
                                             const float* __restrict__ trans,
                                             const int* __restrict__ tags,
                                             float* __restrict__ out) {
  __shared__ float tr[144];
  __shared__ float fvU[NTAG];
  __shared__ float fvP[NTAG];
  __shared__ float pf[160];
  __shared__ float sc[2];
  const int t = threadIdx.x;
  if (t < 144) tr[t] = trans[t];
  if (t < NTAG) {
    fvU[t] = (t == START_TAG) ? 0.f : -100.f;
    fvP[t] = 0.f;
  }
  __syncthreads();
  const int w = t >> 6, l = t & 63;

  if (w == 0) {  // unary forward scan
    float featc = (l < NTAG) ? FU[l] : 0.f;
    for (int step = 0; step < T_SEQ; ++step) {
      float featn = 0.f;
      if (l < NTAG && step + 1 < T_SEQ) featn = FU[(size_t)(step + 1) * NTAG + l];
      if (l < NTAG) {
        float m = -1e30f;
#pragma unroll
        for (int i = 0; i < NTAG; ++i) m = fmaxf(m, fvU[i] + tr[i * NTAG + l]);
        float ss = 0.f;
#pragma unroll
        for (int i = 0; i < NTAG; ++i)
          ss += __expf(fvU[i] + tr[i * NTAG + l] - m);
        fvU[l] = m + __logf(ss) + featc;
      }
      featc = featn;
    }
  } else if (w == 1) {  // pairwise forward scan
    for (int q = l; q < 144; q += 64) pf[q] = FPp[q];
    for (int step = 0; step < T_SEQ + 1; ++step) {
      float nx0 = 0.f, nx1 = 0.f, nx2 = 0.f;
      if (step + 1 < T_SEQ + 1) {
        const float* src = FPp + (size_t)(step + 1) * 144;
        nx0 = src[l];
        nx1 = src[l + 64];
        if (l < 16) nx2 = src[l + 128];
      }
      float nf = 0.f;
      if (l < NTAG) {
        float m = -1e30f;
#pragma unroll
        for (int i = 0; i < NTAG; ++i) m = fmaxf(m, fvP[i] + pf[i * NTAG + l]);
        float ss = 0.f;
#pragma unroll
        for (int i = 0; i < NTAG; ++i)
          ss += __expf(fvP[i] + pf[i * NTAG + l] - m);
        nf = m + __logf(ss);
      }
      pf[l] = nx0;
      pf[l + 64] = nx1;
      if (l < 16) pf[l + 128] = nx2;
      if (l < NTAG) fvP[l] = nf;
    }
  } else if (w == 2) {  // score_u
    float acc = 0.f;
    for (int i = l; i < T_SEQ; i += 64) {
      const int tg = tags[i];
      const int pv = (i == 0) ? START_TAG : tags[i - 1];
      acc += FU[(size_t)i * NTAG + tg] + tr[pv * NTAG + tg];
    }
    if (l == 0) acc += tr[tags[T_SEQ - 1] * NTAG + STOP_TAG];
#pragma unroll
    for (int d = 32; d >= 1; d >>= 1) acc += __shfl_xor(acc, d, 64);
    if (l == 0) sc[0] = acc;
  } else {  // score_p
    float acc = 0.f;
    for (int i = l; i < T_SEQ + 1; i += 64) {
      const int a = (i == 0) ? START_TAG : tags[i - 1];
      const int b2 = (i < T_SEQ) ? tags[i] : STOP_TAG;
      acc += FPp[(size_t)i * 144 + a * NTAG + b2];
    }
#pragma unroll
    for (int d = 32; d >= 1; d >>= 1) acc += __shfl_xor(acc, d, 64);
    if (l == 0) sc[1] = acc;
  }
  __syncthreads();
  if (t == 0) {
    float m = -1e30f;
    for (int i = 0; i < NTAG; ++i)
      m = fmaxf(m, fvU[i] + tr[i * NTAG + STOP_TAG]);
    float ss = 0.f;
    for (int i = 0; i < NTAG; ++i)
      ss += __expf(fvU[i] + tr[i * NTAG + STOP_TAG] - m);
    const float alpha_u = m + __logf(ss);
    float m2 = -1e30f;
    for (int i = 0; i < NTAG; ++i) m2 = fmaxf(m2, fvP[i]);
    float s2 = 0.f;
    for (int i = 0; i < NTAG; ++i) s2 += __expf(fvP[i] - m2);
    const float alpha_p = m2 + __logf(s2);
    out[0] = alpha_u - sc[0] + alpha_p - sc[1];
  }
}

// ---------------------------------------------------------------------------
// Workspace layout (float offsets)
// ---------------------------------------------------------------------------
static const size_t F_XP  = 0;                         // 4*2050*2048
static const size_t F_H0  = 16793600;                  // 4*2050*512
static const size_t F_H1  = 20992000;                  // 4*2050*512
static const size_t F_FC  = 25190400;                  // 2048*1024
static const size_t F_FU  = 27287552;                  // 2048*12
static const size_t F_UB  = 27312128;                  // 2049*512
static const size_t F_HP  = 28361216;                  // 2049*512
static const size_t F_FI  = 29410304;                  // 2049*300
static const size_t F_FO  = 30025004;                  // 2049*300
static const size_t F_FP  = 30639704;                  // 2049*144
static const size_t F_CNT = 30934760;                  // 2*4*2050 ints

extern "C" void kernel_launch(void* const* d_in, const int* in_sizes, int n_in,
                              void* d_out, int out_size, void* d_ws,
                              size_t ws_size, hipStream_t stream) {
  (void)in_sizes; (void)n_in; (void)out_size; (void)ws_size;
  const float* embeds = (const float*)d_in[0];
  const int*   tags   = (const int*)d_in[1];
  const float* uWih   = (const float*)d_in[2];
  const float* uWhh   = (const float*)d_in[3];
  const float* ub     = (const float*)d_in[4];
  const float* pWih   = (const float*)d_in[5];
  const float* pWhh   = (const float*)d_in[6];
  const float* pb     = (const float*)d_in[7];
  const float* ufcW   = (const float*)d_in[8];
  const float* ufcb   = (const float*)d_in[9];
  const float* h2tW   = (const float*)d_in[10];
  const float* h2tb   = (const float*)d_in[11];
  const float* trans  = (const float*)d_in[12];
  const float* UW     = (const float*)d_in[13];
  const float* Ub     = (const float*)d_in[14];
  const float* VW     = (const float*)d_in[15];
  const float* Vb     = (const float*)d_in[16];
  const float* PW     = (const float*)d_in[17];
  const float* Pb     = (const float*)d_in[18];
  const float* pwW    = (const float*)d_in[19];
  const float* pwb    = (const float*)d_in[20];
  const float* ppW    = (const float*)d_in[21];
  const float* ppb    = (const float*)d_in[22];
  float* out = (float*)d_out;
  float* F = (float*)d_ws;
  int* CNT = (int*)(F + F_CNT);

  (void)hipMemsetAsync(CNT, 0, (size_t)2 * 4 * S_SEQ * sizeof(int), stream);

  auto launch = [&](const GemmP& p) {
    dim3 g((p.N + 127) / 128, (p.M + 127) / 128);
    gemm_k<<<g, 256, 0, stream>>>(p);
  };
  auto launch4 = [&](const GemmP& p) {
    dim3 g((p.N + 127) / 128, (p.M + 127) / 128, 4);
    gemm_k<<<g, 256, 0, stream>>>(p);
  };

  // ---- layer-0 xp (4 streams, one dispatch) ----
  {
    GemmP p{};
    p.M = S_SEQ; p.N = 2048; p.K = 1024;
    p.amode = 0; p.A = embeds; p.lda = 1024; p.rowoff = 0;
    p.epi = 0;
    for (int s = 0; s < 4; ++s) {
      const int lstm = s >> 1, d = s & 1;
      p.Wz[s]    = (lstm ? pWih : uWih) + (size_t)d * 2048 * 1024;
      p.biasz[s] = (lstm ? pb : ub) + (size_t)d * 2048;
      p.Cz[s]    = F + F_XP + (size_t)s * S_SEQ * 2048;
      p.revz[s]  = d;
      p.Hfz[s] = nullptr; p.Hbz[s] = nullptr;
    }
    p.W = p.Wz[0]; p.bias = p.biasz[0]; p.C = p.Cz[0]; p.rev = 0;
    launch4(p);
  }
  lstm_layer_k<<<4 * NBLK, 256, 0, stream>>>(uWhh, pWhh, F + F_XP, F + F_H0,
                                             CNT, 0);
  // ---- layer-1 xp (4 streams, one dispatch) ----
  {
    GemmP p{};
    p.M = S_SEQ; p.N = 2048; p.K = 1024;
    p.amode = 1; p.rowoff = 0;
    p.epi = 0;
    for (int s = 0; s < 4; ++s) {
      const int lstm = s >> 1, d = s & 1;
      p.Wz[s]    = (lstm ? pWih : uWih) + (size_t)(2 + d) * 2048 * 1024;
      p.biasz[s] = (lstm ? pb : ub) + (size_t)(2 + d) * 2048;
      p.Cz[s]    = F + F_XP + (size_t)s * S_SEQ * 2048;
      p.revz[s]  = d;
      p.Hfz[s]   = F + F_H0 + (size_t)(lstm * 2 + 0) * S_SEQ * 512;
      p.Hbz[s]   = F + F_H0 + (size_t)(lstm * 2 + 1) * S_SEQ * 512;
    }
    p.W = p.Wz[0]; p.bias = p.biasz[0]; p.C = p.Cz[0]; p.rev = 0;
    p.Hf = p.Hfz[0]; p.Hb = p.Hbz[0];
    launch4(p);
  }
  lstm_layer_k<<<4 * NBLK, 256, 0, stream>>>(uWhh, pWhh, F + F_XP, F + F_H1,
                                             CNT + 4 * S_SEQ, 1);
  // ---- unary head ----
  {
    GemmP p{};
    p.W = ufcW; p.bias = ufcb; p.C = F + F_FC;
    p.M = 2048; p.N = 1024; p.K = 1024;
    p.amode = 1; p.rev = 0; p.rowoff = 1;
    p.Hf = F + F_H1; p.Hb = F + F_H1 + (size_t)1 * S_SEQ * 512;
    p.epi = 1;
    launch(p);
  }
  {
    GemmP p{};
    p.W = h2tW; p.bias = h2tb; p.C = F + F_FU;
    p.M = 2048; p.N = 12; p.K = 1024;
    p.amode = 0; p.A = F + F_FC; p.lda = 1024; p.rev = 0; p.rowoff = 0;
    p.epi = 0;
    launch(p);
  }
  // ---- pairwise head ----
  {
    GemmP p{};
    p.W = UW; p.bias = Ub; p.C = F + F_UB;
    p.M = 2049; p.N = 512; p.K = 1024;
    p.amode = 1; p.rev = 0; p.rowoff = 0;
    p.Hf = F + F_H1 + (size_t)2 * S_SEQ * 512;
    p.Hb = F + F_H1 + (size_t)3 * S_SEQ * 512;
    p.epi = 0;
    launch(p);
  }
  {
    GemmP p{};
    p.W = VW; p.bias = Vb; p.C = F + F_HP;
    p.M = 2049; p.N = 512; p.K = 1024;
    p.amode = 1; p.rev = 0; p.rowoff = 1;
    p.Hf = F + F_H1 + (size_t)2 * S_SEQ * 512;
    p.Hb = F + F_H1 + (size_t)3 * S_SEQ * 512;
    p.epi = 3; p.MUL = F + F_UB;
    launch(p);
  }
  {
    GemmP p{};
    p.W = PW; p.bias = Pb; p.C = F + F_FI;
    p.M = 2049; p.N = 300; p.K = 512;
    p.amode = 0; p.A = F + F_HP; p.lda = 512; p.rev = 0; p.rowoff = 0;
    p.epi = 2;
    launch(p);
  }
  {
    GemmP p{};
    p.W = pwW; p.bias = pwb; p.C = F + F_FO;
    p.M = 2049; p.N = 300; p.K = 300;
    p.amode = 0; p.A = F + F_FI; p.lda = 300; p.rev = 0; p.rowoff = 0;
    p.epi = 1;
    launch(p);
  }
  {
    GemmP p{};
    p.W = ppW; p.bias = ppb; p.C = F + F_FP;
    p.M = 2049; p.N = 144; p.K = 300;
    p.amode = 0; p.A = F + F_FO; p.lda = 300; p.rev = 0; p.rowoff = 0;
    p.epi = 0;
    launch(p);
  }
  crf_k<<<1, 256, 0, stream>>>(F + F_FU, F + F_FP, trans, tags, out);
}